// Round 5
// baseline (717.885 us; speedup 1.0000x reference)
//
#include <hip/hip_runtime.h>
#include <hip/hip_bf16.h>

// Problem constants
#define T_DIM 64
#define B_DIM 512
#define D_DIM 1536
#define H_DIM 1024
#define M_DIM (T_DIM * B_DIM)   // 32768 rows through the MLP
#define DISCOUNT 0.997f
#define LAM 0.95f

// GEMM tiling: 256x256 C-tile, 512 threads (8 waves, 2m x 4n), BK=32.
// QUAD-buffered LDS ring (4 x 32 KB = 128 KB), prefetch depth 3 tiles,
// counted vmcnt(8) at each tile top. ONE barrier per tile; body is left
// to the compiler's counted-lgkm scheduling (R4's sched_barrier walls and
// asm lgkmcnt(0) forbade exactly that interleave and were ~neutral-to-bad).
#define BM 256
#define BN 256
#define BK 32
#define TILES_M (M_DIM / BM)    // 128
#define TILES_N (H_DIM / BN)    // 4
#define N_XCD 8

typedef __bf16 bf16x8 __attribute__((ext_vector_type(8)));
typedef float  f32x4  __attribute__((ext_vector_type(4)));

__device__ __forceinline__ void async_load16(const void* g, void* l) {
    __builtin_amdgcn_global_load_lds(
        (const __attribute__((address_space(1))) void*)g,
        (__attribute__((address_space(3))) void*)l,
        16, 0, 0);
}

__device__ __forceinline__ unsigned short f2bf_raw(float f) {
    __hip_bfloat16 h = __float2bfloat16(f);
    return *reinterpret_cast<unsigned short*>(&h);
}

// ---------------------------------------------------------------------------
// feat fp32 -> bf16, vectorized; also zero-fills the value accumulator
// (gemm layer 4 accumulates the value head into it with atomics).
// ---------------------------------------------------------------------------
__global__ __launch_bounds__(256) void cvt_bf16_kernel(
    const float* __restrict__ x, __hip_bfloat16* __restrict__ y, long n4,
    float* __restrict__ value) {
    long i = (long)blockIdx.x * blockDim.x + threadIdx.x;
    if (i >= n4) return;
    if (i < M_DIM / 4)
        reinterpret_cast<float4*>(value)[i] = (float4){0.f, 0.f, 0.f, 0.f};
    float4 v = reinterpret_cast<const float4*>(x)[i];
    ushort4 o;
    o.x = f2bf_raw(v.x);
    o.y = f2bf_raw(v.y);
    o.z = f2bf_raw(v.z);
    o.w = f2bf_raw(v.w);
    reinterpret_cast<ushort4*>(y)[i] = o;
}

// ---------------------------------------------------------------------------
// All 4 weight transposes in one launch. W (K x N fp32) -> Wt (N x K bf16).
// ---------------------------------------------------------------------------
__global__ __launch_bounds__(256) void transpose_cvt_all_kernel(
    const float* __restrict__ W0, const float* __restrict__ W1,
    const float* __restrict__ W2, const float* __restrict__ W3,
    __hip_bfloat16* __restrict__ T0, __hip_bfloat16* __restrict__ T1,
    __hip_bfloat16* __restrict__ T2, __hip_bfloat16* __restrict__ T3) {
    __shared__ float tile[32][33];
    int z = blockIdx.z;
    const float* W;
    __hip_bfloat16* Tt;
    int K;
    if (z == 0)      { W = W0; Tt = T0; K = D_DIM; }
    else if (z == 1) { W = W1; Tt = T1; K = H_DIM; }
    else if (z == 2) { W = W2; Tt = T2; K = H_DIM; }
    else             { W = W3; Tt = T3; K = H_DIM; }
    int k0 = blockIdx.x * 32, n0 = blockIdx.y * 32;
    if (k0 >= K) return;
    int tx = threadIdx.x, ty = threadIdx.y;  // 32 x 8
    #pragma unroll
    for (int r = ty; r < 32; r += 8)
        tile[r][tx] = W[(size_t)(k0 + r) * H_DIM + n0 + tx];
    __syncthreads();
    #pragma unroll
    for (int r = ty; r < 32; r += 8)
        Tt[(size_t)(n0 + r) * K + k0 + tx] = __float2bfloat16(tile[tx][r]);
}

// ---------------------------------------------------------------------------
// C[m][n] = silu( sum_k A[m][k] * Bt[n][k] + bias[n] ), output bf16.
// If value != nullptr (layer 4): skip the C store entirely and accumulate
// value[m] += sum_n silu(...) * Wo[n] via quad-shuffle + LDS reduce + one
// f32 atomicAdd per row per block (removes the 64MB Hb write + 64MB gemv
// read + one dispatch).
//
// Main loop per K-tile (BK=32, ring of 4 slots, depth-3 prefetch):
//   s_waitcnt vmcnt(8)   -- tile t's 4 loads retired (t+1,t+2 in flight)
//   s_barrier            -- broadcasts readiness (each wave only counts its
//                           own loads; barrier makes it collective)
//   stage tile t+3       -- slot (t-1)&3; safe: all waves' t-1 reads
//                           completed before they reached this barrier
//   12 ds_read_b128 + 32 MFMA, compiler-scheduled (counted lgkmcnt
//   interleave, m97-style). No other barriers, no sched walls, no setprio.
//
// Swizzle (verified 0 conflicts in R3/R4): granule = 4*(row&1) +
// (colgrp ^ ((row>>1)&3)); staging source column uses the same permutation.
// C^T operand order (verified R3/R4): acc = mfma(B-frag, A-frag):
// m = lane&15, regs = 4 consecutive n.
// ---------------------------------------------------------------------------
__global__ __launch_bounds__(512, 2) void gemm_silu_kernel(
    const __hip_bfloat16* __restrict__ A,
    const __hip_bfloat16* __restrict__ Bt,
    const float* __restrict__ bias,
    __hip_bfloat16* __restrict__ C,
    int K,
    const float* __restrict__ Wo,
    float* __restrict__ value) {

    __shared__ alignas(16) __hip_bfloat16 lds[65536];   // 128 KB

    const int tid  = threadIdx.x;
    const int wave = tid >> 6;         // 0..7
    const int lane = tid & 63;
    const int quad = lane >> 4;        // 0..3 (k-slice of fragment)
    const int r16  = lane & 15;        // 0..15
    const int wm   = wave & 1;         // wave row in 2x4
    const int wn   = wave >> 1;        // wave col in 2x4 (0..3)

    // XCD-aware tile assignment: 512 blocks = 128 M-tiles x 4 N-tiles
    const int l     = blockIdx.x;
    const int xcd   = l & (N_XCD - 1);
    const int local = l >> 3;                    // 0..63
    const int tn    = local & (TILES_N - 1);     // 0..3
    const int tm    = (xcd << 4) | (local >> 2); // 0..127
    const int m0 = tm * BM;
    const int n0 = tn * BN;

    // --- staging geometry: one global_load_lds covers 16 rows x 32 cols.
    // lane -> row lane>>2, col group lane&3. Source col pre-swizzled with
    // s(row) = (row>>1)&3.
    const int rsub = lane >> 2;                       // 0..15
    const int cgrp = lane & 3;                        // 0..3
    const int scol = ((cgrp ^ ((rsub >> 1) & 3)) << 3);
    const __hip_bfloat16* gA = A  + (size_t)(m0 + wave * 32 + rsub) * K + scol;
    const __hip_bfloat16* gB = Bt + (size_t)(n0 + wave * 32 + rsub) * K + scol;
    const int ldsOf0 = (wave * 32) * 32;              // elems within a buf
    const int ldsOf1 = (wave * 32 + 16) * 32;

    // --- fragment read offsets (elems within a buf), swizzled to match
    const int swz    = ((quad ^ ((r16 >> 1) & 3)) << 3);
    const int rdoffA = (wm * 128 + r16) * 32 + swz;
    const int rdoffB = (wn * 64  + r16) * 32 + swz;

    f32x4 acc[8][4];
    #pragma unroll
    for (int i = 0; i < 8; ++i)
        #pragma unroll
        for (int j = 0; j < 4; ++j)
            acc[i][j] = (f32x4){0.f, 0.f, 0.f, 0.f};

#define STAGE(tt) do { \
        const int sbb = (tt) & 3; \
        __hip_bfloat16* Ab_ = &lds[sbb * 8192]; \
        __hip_bfloat16* Bb_ = &lds[32768 + sbb * 8192]; \
        const size_t ko_ = (size_t)(tt) * BK; \
        async_load16(gA + ko_,                  Ab_ + ldsOf0); \
        async_load16(gA + ko_ + (size_t)16 * K, Ab_ + ldsOf1); \
        async_load16(gB + ko_,                  Bb_ + ldsOf0); \
        async_load16(gB + ko_ + (size_t)16 * K, Bb_ + ldsOf1); \
    } while (0)

#define RD_A(i) (*reinterpret_cast<const bf16x8*>(Ab + rdoffA + (i) * 512))
#define RD_B(j) (*reinterpret_cast<const bf16x8*>(Bb + rdoffB + (j) * 512))

#define BODY(t, VMCNT, DOSTAGE) do { \
        asm volatile("s_waitcnt vmcnt(" #VMCNT ")" ::: "memory"); \
        __builtin_amdgcn_s_barrier(); \
        if (DOSTAGE) STAGE((t) + 3); \
        const int bb = (t) & 3; \
        const __hip_bfloat16* Ab = &lds[bb * 8192]; \
        const __hip_bfloat16* Bb = &lds[32768 + bb * 8192]; \
        bf16x8 bfr[4], af[8]; \
        _Pragma("unroll") \
        for (int j = 0; j < 4; ++j) bfr[j] = RD_B(j); \
        _Pragma("unroll") \
        for (int i = 0; i < 8; ++i) af[i] = RD_A(i); \
        _Pragma("unroll") \
        for (int i = 0; i < 8; ++i) \
            _Pragma("unroll") \
            for (int j = 0; j < 4; ++j) \
                acc[i][j] = __builtin_amdgcn_mfma_f32_16x16x32_bf16( \
                    bfr[j], af[i], acc[i][j], 0, 0, 0); \
    } while (0)

    // prologue: stage tiles 0..2 (12 wave-instrs outstanding)
    STAGE(0); STAGE(1); STAGE(2);

    const int NT = K / BK;   // 48 or 32
    for (int t = 0; t < NT - 2; ++t)
        BODY(t, 8, (t + 3 < NT));
    BODY(NT - 2, 4, false);
    BODY(NT - 1, 0, false);

#undef STAGE
#undef RD_A
#undef RD_B
#undef BODY

    if (value == nullptr) {
        // epilogue: bias + SiLU + packed 8-B stores.
        // C^T fragment layout: m = lane&15 (block i), n = j*16 + quad*4 + rr.
        #pragma unroll
        for (int j = 0; j < 4; ++j) {
            const int c0 = n0 + wn * 64 + j * 16 + quad * 4;
            const float4 b4 = *reinterpret_cast<const float4*>(&bias[c0]);
            const float* bp = reinterpret_cast<const float*>(&b4);
            #pragma unroll
            for (int i = 0; i < 8; ++i) {
                const int row = m0 + wm * 128 + i * 16 + r16;
                ushort4 o;
                unsigned short* op = reinterpret_cast<unsigned short*>(&o);
                #pragma unroll
                for (int rr = 0; rr < 4; ++rr) {
                    const float v = acc[i][j][rr] + bp[rr];
                    const float s = v / (1.f + __expf(-v));
                    op[rr] = f2bf_raw(s);
                }
                *reinterpret_cast<ushort4*>(&C[(size_t)row * H_DIM + c0]) = o;
            }
        }
    } else {
        // layer-4 epilogue: value[m] += sum_n silu(acc + bias) * Wo[n].
        // Per lane: 8 row-partials over its 16 cols; quad-shuffle reduce
        // (xor 16, 32) -> 64-col wave partial; LDS reduce across wn; one
        // atomicAdd per row per block. No C store (Hb is dead).
        float part[8];
        #pragma unroll
        for (int i = 0; i < 8; ++i) part[i] = 0.f;
        #pragma unroll
        for (int j = 0; j < 4; ++j) {
            const int c0 = n0 + wn * 64 + j * 16 + quad * 4;
            const float4 b4 = *reinterpret_cast<const float4*>(&bias[c0]);
            const float4 w4 = *reinterpret_cast<const float4*>(&Wo[c0]);
            const float* bp = reinterpret_cast<const float*>(&b4);
            const float* wp = reinterpret_cast<const float*>(&w4);
            #pragma unroll
            for (int i = 0; i < 8; ++i) {
                #pragma unroll
                for (int rr = 0; rr < 4; ++rr) {
                    const float v = acc[i][j][rr] + bp[rr];
                    const float s = v / (1.f + __expf(-v));
                    part[i] += s * wp[rr];
                }
            }
        }
        __syncthreads();  // all MFMA reads done; LDS reusable
        float* lds_v = reinterpret_cast<float*>(lds);   // [256][4]
        #pragma unroll
        for (int i = 0; i < 8; ++i) {
            float p = part[i];
            p += __shfl_xor(p, 16, 64);
            p += __shfl_xor(p, 32, 64);
            if (quad == 0)
                lds_v[(wm * 128 + i * 16 + r16) * 4 + wn] = p;
        }
        __syncthreads();
        if (tid < 256) {
            const float* row = &lds_v[tid * 4];
            atomicAdd(&value[m0 + tid], row[0] + row[1] + row[2] + row[3]);
        }
    }
}

// ---------------------------------------------------------------------------
// GAE backward scan. value: (T,B) fp32 (pre-bias; bo added here).
// out: ret (63x512) then baseline.
// ---------------------------------------------------------------------------
__global__ __launch_bounds__(64) void gae_kernel(
    const float* __restrict__ value,
    const float* __restrict__ reward,
    const float* __restrict__ cont,
    const float* __restrict__ bo_p,
    float* __restrict__ out) {
    int b = blockIdx.x * blockDim.x + threadIdx.x;
    if (b >= B_DIM) return;
    const float bo = bo_p[0];
    float adv = 0.f;
    float v_next = value[(T_DIM - 1) * B_DIM + b] + bo;
    for (int t = T_DIM - 2; t >= 0; --t) {
        float v_t  = value[t * B_DIM + b] + bo;
        float disc = cont[(t + 1) * B_DIM + b] * DISCOUNT;
        float delta = reward[t * B_DIM + b] + disc * v_next - v_t;
        adv = delta + disc * LAM * adv;
        out[t * B_DIM + b] = adv + v_t;                           // ret
        out[(T_DIM - 1) * B_DIM + t * B_DIM + b] = v_t;           // baseline
        v_next = v_t;
    }
}

// ---------------------------------------------------------------------------
extern "C" void kernel_launch(void* const* d_in, const int* in_sizes, int n_in,
                              void* d_out, int out_size, void* d_ws, size_t ws_size,
                              hipStream_t stream) {
    const float* feat   = (const float*)d_in[0];
    const float* reward = (const float*)d_in[1];
    const float* cont   = (const float*)d_in[2];
    const float* W[4]   = {(const float*)d_in[3], (const float*)d_in[5],
                           (const float*)d_in[7], (const float*)d_in[9]};
    const float* bias[4] = {(const float*)d_in[4], (const float*)d_in[6],
                            (const float*)d_in[8], (const float*)d_in[10]};
    const float* Wo = (const float*)d_in[11];
    const float* bo = (const float*)d_in[12];
    float* out = (float*)d_out;

    // workspace layout
    char* ws = (char*)d_ws;
    __hip_bfloat16* Xb = (__hip_bfloat16*)ws; ws += (size_t)M_DIM * D_DIM * 2;   // 96 MB
    __hip_bfloat16* Ha = (__hip_bfloat16*)ws; ws += (size_t)M_DIM * H_DIM * 2;   // 64 MB
    __hip_bfloat16* Hb = (__hip_bfloat16*)ws; ws += (size_t)M_DIM * H_DIM * 2;   // 64 MB
    __hip_bfloat16* Wt0 = (__hip_bfloat16*)ws; ws += (size_t)H_DIM * D_DIM * 2;  // 3 MB
    __hip_bfloat16* Wt1 = (__hip_bfloat16*)ws; ws += (size_t)H_DIM * H_DIM * 2;
    __hip_bfloat16* Wt2 = (__hip_bfloat16*)ws; ws += (size_t)H_DIM * H_DIM * 2;
    __hip_bfloat16* Wt3 = (__hip_bfloat16*)ws; ws += (size_t)H_DIM * H_DIM * 2;
    float* value = (float*)ws; ws += (size_t)M_DIM * 4;

    // 1. feat -> bf16 (also zeroes value for the layer-4 atomic reduction)
    long n4 = (long)M_DIM * D_DIM / 4;
    cvt_bf16_kernel<<<(int)((n4 + 255) / 256), 256, 0, stream>>>(feat, Xb, n4, value);

    // 2. all weight transposes, one launch
    transpose_cvt_all_kernel<<<dim3(D_DIM / 32, H_DIM / 32, 4), dim3(32, 8), 0, stream>>>(
        W[0], W[1], W[2], W[3], Wt0, Wt1, Wt2, Wt3);

    // 3. MLP: 4 GEMM + SiLU layers; layer 4 fuses the value-head GEMV
    const int nblocks = TILES_M * TILES_N;  // 512
    gemm_silu_kernel<<<nblocks, 512, 0, stream>>>(Xb, Wt0, bias[0], Ha, D_DIM,
                                                  nullptr, nullptr);
    gemm_silu_kernel<<<nblocks, 512, 0, stream>>>(Ha, Wt1, bias[1], Hb, H_DIM,
                                                  nullptr, nullptr);
    gemm_silu_kernel<<<nblocks, 512, 0, stream>>>(Hb, Wt2, bias[2], Ha, H_DIM,
                                                  nullptr, nullptr);
    gemm_silu_kernel<<<nblocks, 512, 0, stream>>>(Ha, Wt3, bias[3], Hb, H_DIM,
                                                  Wo, value);

    // 4. GAE scan (adds bo to value here)
    gae_kernel<<<8, 64, 0, stream>>>(value, reward, cont, bo, out);
}

// Round 6
// 673.835 us; speedup vs baseline: 1.0654x; 1.0654x over previous
//
#include <hip/hip_runtime.h>
#include <hip/hip_bf16.h>

// Problem constants
#define T_DIM 64
#define B_DIM 512
#define D_DIM 1536
#define H_DIM 1024
#define M_DIM (T_DIM * B_DIM)   // 32768 rows through the MLP
#define DISCOUNT 0.997f
#define LAM 0.95f

// GEMM tiling: 128x256 C-tile, 512 threads (8 waves, 2m x 4n), BK=64.
// Single-buffered 48 KB LDS -> 3 blocks/CU. Ground-truth audit (R0..R5):
// this high-TLP structure beats every 1-block/CU deep-pipeline variant in
// real (graph-captured) runs, even though those profile better in isolated
// rocprof replays (warm-cache artifact). Keep the structure; optimize only
// the epilogue and the kernel graph around it.
#define BM 128
#define BN 256
#define BK 64
#define TILES_M 256
#define TILES_N 4
#define N_XCD 8

typedef __bf16 bf16x8 __attribute__((ext_vector_type(8)));
typedef float  f32x4  __attribute__((ext_vector_type(4)));

__device__ __forceinline__ void async_load16(const void* g, void* l) {
    __builtin_amdgcn_global_load_lds(
        (const __attribute__((address_space(1))) void*)g,
        (__attribute__((address_space(3))) void*)l,
        16, 0, 0);
}

__device__ __forceinline__ unsigned short f2bf_raw(float f) {
    __hip_bfloat16 h = __float2bfloat16(f);
    return *reinterpret_cast<unsigned short*>(&h);
}

// ---------------------------------------------------------------------------
// feat fp32 -> bf16, vectorized; also zero-fills the value accumulator
// (gemm layer 4 accumulates the value head into it with atomics).
// ---------------------------------------------------------------------------
__global__ __launch_bounds__(256) void cvt_bf16_kernel(
    const float* __restrict__ x, __hip_bfloat16* __restrict__ y, long n4,
    float* __restrict__ value) {
    long i = (long)blockIdx.x * blockDim.x + threadIdx.x;
    if (i >= n4) return;
    if (i < M_DIM / 4)
        reinterpret_cast<float4*>(value)[i] = (float4){0.f, 0.f, 0.f, 0.f};
    float4 v = reinterpret_cast<const float4*>(x)[i];
    ushort4 o;
    o.x = f2bf_raw(v.x);
    o.y = f2bf_raw(v.y);
    o.z = f2bf_raw(v.z);
    o.w = f2bf_raw(v.w);
    reinterpret_cast<ushort4*>(y)[i] = o;
}

// ---------------------------------------------------------------------------
// All 4 weight transposes in one launch. W (K x N fp32) -> Wt (N x K bf16).
// ---------------------------------------------------------------------------
__global__ __launch_bounds__(256) void transpose_cvt_all_kernel(
    const float* __restrict__ W0, const float* __restrict__ W1,
    const float* __restrict__ W2, const float* __restrict__ W3,
    __hip_bfloat16* __restrict__ T0, __hip_bfloat16* __restrict__ T1,
    __hip_bfloat16* __restrict__ T2, __hip_bfloat16* __restrict__ T3) {
    __shared__ float tile[32][33];
    int z = blockIdx.z;
    const float* W;
    __hip_bfloat16* Tt;
    int K;
    if (z == 0)      { W = W0; Tt = T0; K = D_DIM; }
    else if (z == 1) { W = W1; Tt = T1; K = H_DIM; }
    else if (z == 2) { W = W2; Tt = T2; K = H_DIM; }
    else             { W = W3; Tt = T3; K = H_DIM; }
    int k0 = blockIdx.x * 32, n0 = blockIdx.y * 32;
    if (k0 >= K) return;
    int tx = threadIdx.x, ty = threadIdx.y;  // 32 x 8
    #pragma unroll
    for (int r = ty; r < 32; r += 8)
        tile[r][tx] = W[(size_t)(k0 + r) * H_DIM + n0 + tx];
    __syncthreads();
    #pragma unroll
    for (int r = ty; r < 32; r += 8)
        Tt[(size_t)(n0 + r) * K + k0 + tx] = __float2bfloat16(tile[tx][r]);
}

// ---------------------------------------------------------------------------
// C[m][n] = silu( sum_k A[m][k] * Bt[n][k] + bias[n] ), output bf16.
// R0 structure (ground-truth best): 128x256 tile, 8 waves (2m x 4n), BK=64,
// single-buffered 48 KB LDS, 3 blocks/CU, two __syncthreads per K-tile;
// cross-block wave overlap covers the barrier drains.
//
// Grafted wins (verified in R3/R5, orthogonal to the structure):
//  - MFMA operands swapped: acc = mfma(bf, af) computes the C^T fragment
//    (m = lane&15, regs = 4 consecutive n) -> epilogue packs 4 bf16 cols
//    into one 8-B ushort4 store (R3: WRITE_SIZE 137->114 MB, FP-identical).
//  - If value != nullptr (layer 4): no C store at all; accumulate
//    value[m] += sum_n silu(...)*Wo[n] via quad-shuffle + LDS reduce + one
//    f32 atomicAdd per row per block (kills gemv dispatch + 64MB write +
//    64MB read; R5 verified identical absmax).
//
// XCD swizzle: hw block l -> xcd = l%8; 4 adjacent local blocks share one
// A panel on the same XCD. LDS XOR swizzle via permuted global source
// column: conflict-free (R0 measured SQ_LDS_BANK_CONFLICT = 0).
// ---------------------------------------------------------------------------
__global__ __launch_bounds__(512, 4) void gemm_silu_kernel(
    const __hip_bfloat16* __restrict__ A,
    const __hip_bfloat16* __restrict__ Bt,
    const float* __restrict__ bias,
    __hip_bfloat16* __restrict__ C,
    int K,
    const float* __restrict__ Wo,
    float* __restrict__ value) {

    __shared__ alignas(16) __hip_bfloat16 As[BM * BK];  // 16 KB
    __shared__ alignas(16) __hip_bfloat16 Bs[BN * BK];  // 32 KB

    const int tid  = threadIdx.x;
    const int wave = tid >> 6;         // 0..7
    const int lane = tid & 63;
    const int sub  = lane >> 3;        // staging row within 8-row chunk
    const int quad = lane >> 4;        // 0..3
    const int r16  = lane & 15;        // 0..15
    const int wm   = wave & 1;         // wave row in 2x4
    const int wn   = wave >> 1;        // wave col in 2x4 (0..3)

    // XCD-aware tile assignment: 1024 blocks = 256 M-tiles x 4 N-tiles
    const int l     = blockIdx.x;
    const int xcd   = l & (N_XCD - 1);
    const int local = l >> 3;                  // 0..127
    const int tn    = local & (TILES_N - 1);   // 0..3
    const int tm    = (xcd << 5) | (local >> 2);
    const int m0 = tm * BM;
    const int n0 = tn * BN;

    // swizzled global column for this lane's staging load
    const int scol = (((lane & 7) ^ sub) << 3);

    // staging pointers: A chunks {2w, 2w+1} (16 chunks of 8 rows),
    //                   B chunks {4w..4w+3} (32 chunks of 8 rows)
    const __hip_bfloat16* ga[2];
    const __hip_bfloat16* gb[4];
    #pragma unroll
    for (int i = 0; i < 2; ++i)
        ga[i] = A + (size_t)(m0 + (wave * 2 + i) * 8 + sub) * K + scol;
    #pragma unroll
    for (int i = 0; i < 4; ++i)
        gb[i] = Bt + (size_t)(n0 + (wave * 4 + i) * 8 + sub) * K + scol;

    f32x4 acc[4][4];
    #pragma unroll
    for (int i = 0; i < 4; ++i)
        #pragma unroll
        for (int j = 0; j < 4; ++j)
            acc[i][j] = (f32x4){0.f, 0.f, 0.f, 0.f};

    for (int k0 = 0; k0 < K; k0 += BK) {
        #pragma unroll
        for (int i = 0; i < 2; ++i) {
            async_load16(ga[i], &As[(wave * 2 + i) * 512]);
            ga[i] += BK;
        }
        #pragma unroll
        for (int i = 0; i < 4; ++i) {
            async_load16(gb[i], &Bs[(wave * 4 + i) * 512]);
            gb[i] += BK;
        }
        __syncthreads();

        #pragma unroll
        for (int kk = 0; kk < BK; kk += 32) {
            bf16x8 af[4], bf[4];
            #pragma unroll
            for (int i = 0; i < 4; ++i) {
                int m_l = wm * 64 + i * 16 + r16;
                int sa  = ((kk >> 3) + quad) ^ (m_l & 7);
                af[i] = *reinterpret_cast<const bf16x8*>(&As[m_l * BK + sa * 8]);
                int n_l = wn * 64 + i * 16 + r16;
                int sb  = ((kk >> 3) + quad) ^ (n_l & 7);
                bf[i] = *reinterpret_cast<const bf16x8*>(&Bs[n_l * BK + sb * 8]);
            }
            // C^T accumulation: mfma(B-frag, A-frag) -> m = lane&15, regs = n
            #pragma unroll
            for (int i = 0; i < 4; ++i)
                #pragma unroll
                for (int j = 0; j < 4; ++j)
                    acc[i][j] = __builtin_amdgcn_mfma_f32_16x16x32_bf16(
                        bf[j], af[i], acc[i][j], 0, 0, 0);
        }
        __syncthreads();
    }

    if (value == nullptr) {
        // epilogue: bias + SiLU + packed 8-B stores.
        // C^T layout: row = m0+wm*64+i*16+(lane&15), n = j*16+quad*4+rr.
        #pragma unroll
        for (int j = 0; j < 4; ++j) {
            const int c0 = n0 + wn * 64 + j * 16 + quad * 4;
            const float4 b4 = *reinterpret_cast<const float4*>(&bias[c0]);
            const float* bp = reinterpret_cast<const float*>(&b4);
            #pragma unroll
            for (int i = 0; i < 4; ++i) {
                const int row = m0 + wm * 64 + i * 16 + r16;
                ushort4 o;
                unsigned short* op = reinterpret_cast<unsigned short*>(&o);
                #pragma unroll
                for (int rr = 0; rr < 4; ++rr) {
                    const float v = acc[i][j][rr] + bp[rr];
                    const float s = v / (1.f + __expf(-v));
                    op[rr] = f2bf_raw(s);
                }
                *reinterpret_cast<ushort4*>(&C[(size_t)row * H_DIM + c0]) = o;
            }
        }
    } else {
        // layer-4 epilogue: value[m] += sum_n silu(acc + bias) * Wo[n].
        // Per lane: 4 row-partials over its 16 cols; quad-shuffle reduce
        // (xor 16, 32) -> 64-col wave partial; LDS reduce across wn; one
        // atomicAdd per row per block. No C store (Hb round-trip is dead).
        float part[4];
        #pragma unroll
        for (int i = 0; i < 4; ++i) part[i] = 0.f;
        #pragma unroll
        for (int j = 0; j < 4; ++j) {
            const int c0 = n0 + wn * 64 + j * 16 + quad * 4;
            const float4 b4 = *reinterpret_cast<const float4*>(&bias[c0]);
            const float4 w4 = *reinterpret_cast<const float4*>(&Wo[c0]);
            const float* bp = reinterpret_cast<const float*>(&b4);
            const float* wp = reinterpret_cast<const float*>(&w4);
            #pragma unroll
            for (int i = 0; i < 4; ++i) {
                #pragma unroll
                for (int rr = 0; rr < 4; ++rr) {
                    const float v = acc[i][j][rr] + bp[rr];
                    const float s = v / (1.f + __expf(-v));
                    part[i] += s * wp[rr];
                }
            }
        }
        // last loop iteration ended with __syncthreads(): all LDS reads done,
        // safe to repurpose As as float[128][4].
        float* lds_v = reinterpret_cast<float*>(As);
        #pragma unroll
        for (int i = 0; i < 4; ++i) {
            float p = part[i];
            p += __shfl_xor(p, 16, 64);
            p += __shfl_xor(p, 32, 64);
            if (quad == 0)
                lds_v[(wm * 64 + i * 16 + r16) * 4 + wn] = p;
        }
        __syncthreads();
        if (tid < BM) {
            const float* row = &lds_v[tid * 4];
            atomicAdd(&value[m0 + tid], row[0] + row[1] + row[2] + row[3]);
        }
    }
}

// ---------------------------------------------------------------------------
// GAE backward scan. value: (T,B) fp32 (pre-bias; bo added here).
// out: ret (63x512) then baseline.
// ---------------------------------------------------------------------------
__global__ __launch_bounds__(64) void gae_kernel(
    const float* __restrict__ value,
    const float* __restrict__ reward,
    const float* __restrict__ cont,
    const float* __restrict__ bo_p,
    float* __restrict__ out) {
    int b = blockIdx.x * blockDim.x + threadIdx.x;
    if (b >= B_DIM) return;
    const float bo = bo_p[0];
    float adv = 0.f;
    float v_next = value[(T_DIM - 1) * B_DIM + b] + bo;
    for (int t = T_DIM - 2; t >= 0; --t) {
        float v_t  = value[t * B_DIM + b] + bo;
        float disc = cont[(t + 1) * B_DIM + b] * DISCOUNT;
        float delta = reward[t * B_DIM + b] + disc * v_next - v_t;
        adv = delta + disc * LAM * adv;
        out[t * B_DIM + b] = adv + v_t;                           // ret
        out[(T_DIM - 1) * B_DIM + t * B_DIM + b] = v_t;           // baseline
        v_next = v_t;
    }
}

// ---------------------------------------------------------------------------
extern "C" void kernel_launch(void* const* d_in, const int* in_sizes, int n_in,
                              void* d_out, int out_size, void* d_ws, size_t ws_size,
                              hipStream_t stream) {
    const float* feat   = (const float*)d_in[0];
    const float* reward = (const float*)d_in[1];
    const float* cont   = (const float*)d_in[2];
    const float* W[4]   = {(const float*)d_in[3], (const float*)d_in[5],
                           (const float*)d_in[7], (const float*)d_in[9]};
    const float* bias[4] = {(const float*)d_in[4], (const float*)d_in[6],
                            (const float*)d_in[8], (const float*)d_in[10]};
    const float* Wo = (const float*)d_in[11];
    const float* bo = (const float*)d_in[12];
    float* out = (float*)d_out;

    // workspace layout
    char* ws = (char*)d_ws;
    __hip_bfloat16* Xb = (__hip_bfloat16*)ws; ws += (size_t)M_DIM * D_DIM * 2;   // 96 MB
    __hip_bfloat16* Ha = (__hip_bfloat16*)ws; ws += (size_t)M_DIM * H_DIM * 2;   // 64 MB
    __hip_bfloat16* Hb = (__hip_bfloat16*)ws; ws += (size_t)M_DIM * H_DIM * 2;   // 64 MB
    __hip_bfloat16* Wt0 = (__hip_bfloat16*)ws; ws += (size_t)H_DIM * D_DIM * 2;  // 3 MB
    __hip_bfloat16* Wt1 = (__hip_bfloat16*)ws; ws += (size_t)H_DIM * H_DIM * 2;
    __hip_bfloat16* Wt2 = (__hip_bfloat16*)ws; ws += (size_t)H_DIM * H_DIM * 2;
    __hip_bfloat16* Wt3 = (__hip_bfloat16*)ws; ws += (size_t)H_DIM * H_DIM * 2;
    float* value = (float*)ws; ws += (size_t)M_DIM * 4;

    // 1. feat -> bf16 (also zeroes value for the layer-4 atomic reduction)
    long n4 = (long)M_DIM * D_DIM / 4;
    cvt_bf16_kernel<<<(int)((n4 + 255) / 256), 256, 0, stream>>>(feat, Xb, n4, value);

    // 2. all weight transposes, one launch
    transpose_cvt_all_kernel<<<dim3(D_DIM / 32, H_DIM / 32, 4), dim3(32, 8), 0, stream>>>(
        W[0], W[1], W[2], W[3], Wt0, Wt1, Wt2, Wt3);

    // 3. MLP: 4 GEMM + SiLU layers; layer 4 fuses the value-head GEMV
    const int nblocks = TILES_M * TILES_N;  // 1024
    gemm_silu_kernel<<<nblocks, 512, 0, stream>>>(Xb, Wt0, bias[0], Ha, D_DIM,
                                                  nullptr, nullptr);
    gemm_silu_kernel<<<nblocks, 512, 0, stream>>>(Ha, Wt1, bias[1], Hb, H_DIM,
                                                  nullptr, nullptr);
    gemm_silu_kernel<<<nblocks, 512, 0, stream>>>(Hb, Wt2, bias[2], Ha, H_DIM,
                                                  nullptr, nullptr);
    gemm_silu_kernel<<<nblocks, 512, 0, stream>>>(Ha, Wt3, bias[3], Hb, H_DIM,
                                                  Wo, value);

    // 4. GAE scan (adds bo to value here)
    gae_kernel<<<8, 64, 0, stream>>>(value, reward, cont, bo, out);
}

// Round 7
// 660.256 us; speedup vs baseline: 1.0873x; 1.0206x over previous
//
#include <hip/hip_runtime.h>
#include <hip/hip_bf16.h>

// Problem constants
#define T_DIM 64
#define B_DIM 512
#define D_DIM 1536
#define H_DIM 1024
#define M_DIM (T_DIM * B_DIM)   // 32768 rows through the MLP
#define DISCOUNT 0.997f
#define LAM 0.95f

// GEMM tiling: 128x256 C-tile, 512 threads (8 waves, 2m x 4n), BK=64.
// Single-buffered 48 KB LDS -> 3 blocks/CU. Ground-truth audit (R0..R6):
// this high-TLP structure beats every 1-block/CU deep-pipeline variant in
// real (graph-captured) runs. Keep the structure; optimize real work around
// it. R7: the fp32->bf16 cvt pass (288 MB, ~50us) is deleted; layer 1
// reg-stages fp32 feat directly (bit-identical LDS image).
#define BM 128
#define BN 256
#define BK 64
#define TILES_M 256
#define TILES_N 4
#define N_XCD 8

typedef __bf16 bf16x8 __attribute__((ext_vector_type(8)));
typedef float  f32x4  __attribute__((ext_vector_type(4)));

__device__ __forceinline__ void async_load16(const void* g, void* l) {
    __builtin_amdgcn_global_load_lds(
        (const __attribute__((address_space(1))) void*)g,
        (__attribute__((address_space(3))) void*)l,
        16, 0, 0);
}

__device__ __forceinline__ unsigned short f2bf_raw(float f) {
    __hip_bfloat16 h = __float2bfloat16(f);
    return *reinterpret_cast<unsigned short*>(&h);
}

__device__ __forceinline__ unsigned int pack2bf(float lo, float hi) {
    return ((unsigned int)f2bf_raw(hi) << 16) | (unsigned int)f2bf_raw(lo);
}

// ---------------------------------------------------------------------------
// All 4 weight transposes in one launch. W (K x N fp32) -> Wt (N x K bf16).
// Also zero-fills the value accumulator (layer 4 atomically accumulates the
// fused value head into it; this kernel always runs before layer 4).
// ---------------------------------------------------------------------------
__global__ __launch_bounds__(256) void transpose_cvt_all_kernel(
    const float* __restrict__ W0, const float* __restrict__ W1,
    const float* __restrict__ W2, const float* __restrict__ W3,
    __hip_bfloat16* __restrict__ T0, __hip_bfloat16* __restrict__ T1,
    __hip_bfloat16* __restrict__ T2, __hip_bfloat16* __restrict__ T3,
    float* __restrict__ value) {
    __shared__ float tile[32][33];
    int tx = threadIdx.x, ty = threadIdx.y;  // 32 x 8
    // value zero-init: z==0,y==0 slice (48 blocks x 256 threads >= 8192 f4)
    if (blockIdx.z == 0 && blockIdx.y == 0) {
        int idx = blockIdx.x * 256 + ty * 32 + tx;
        if (idx < M_DIM / 4)
            reinterpret_cast<float4*>(value)[idx] = (float4){0.f, 0.f, 0.f, 0.f};
    }
    int z = blockIdx.z;
    const float* W;
    __hip_bfloat16* Tt;
    int K;
    if (z == 0)      { W = W0; Tt = T0; K = D_DIM; }
    else if (z == 1) { W = W1; Tt = T1; K = H_DIM; }
    else if (z == 2) { W = W2; Tt = T2; K = H_DIM; }
    else             { W = W3; Tt = T3; K = H_DIM; }
    int k0 = blockIdx.x * 32, n0 = blockIdx.y * 32;
    if (k0 >= K) return;
    #pragma unroll
    for (int r = ty; r < 32; r += 8)
        tile[r][tx] = W[(size_t)(k0 + r) * H_DIM + n0 + tx];
    __syncthreads();
    #pragma unroll
    for (int r = ty; r < 32; r += 8)
        Tt[(size_t)(n0 + r) * K + k0 + tx] = __float2bfloat16(tile[tx][r]);
}

// ---------------------------------------------------------------------------
// C[m][n] = silu( sum_k A[m][k] * Bt[n][k] + bias[n] ), output bf16.
// R0 structure (ground-truth best): 128x256 tile, 8 waves (2m x 4n), BK=64,
// single-buffered 48 KB LDS, 3 blocks/CU, two __syncthreads per K-tile.
//
// L1 template arg (R7): layer 1 reads feat fp32 directly. A-staging becomes
// reg-staging: per chunk, lane loads 2 x float4 (cols (cg^sub)*8..+7 fp32),
// packs to 8 bf16 with __float2bfloat16 (same rounding as the old cvt pass
// -> bit-identical LDS image, same swizzle), one 16-B ds_write at the same
// address global_load_lds would have used. B keeps global_load_lds. Barrier
// structure unchanged: ds_write happens after the previous iteration's
// trailing barrier (all LDS reads done), staging barrier drains lgkm+vmcnt.
// This deletes the 288-MB cvt dispatch; feat re-reads by sibling N-blocks
// are same-XCD L2/L3 hits.
//
// Verified grafts (R3/R5/R6):
//  - C^T MFMA operand order: acc = mfma(bf, af): m = lane&15, regs = 4
//    consecutive n -> packed 8-B epilogue stores (WRITE_SIZE 137->67 MB).
//  - value != nullptr (layer 4): no C store; value[m] += sum_n silu*Wo[n]
//    via quad-shuffle + LDS reduce + 1 atomicAdd/row/block.
//
// XCD swizzle: 4 sibling N-blocks of an M-tile share one XCD. LDS XOR
// swizzle via permuted source column: SQ_LDS_BANK_CONFLICT = 0 (measured).
// ---------------------------------------------------------------------------
template<bool L1>
__global__ __launch_bounds__(512, 4) void gemm_silu_kernel(
    const __hip_bfloat16* __restrict__ A,
    const float* __restrict__ Af,
    const __hip_bfloat16* __restrict__ Bt,
    const float* __restrict__ bias,
    __hip_bfloat16* __restrict__ C,
    int K,
    const float* __restrict__ Wo,
    float* __restrict__ value) {

    __shared__ alignas(16) __hip_bfloat16 As[BM * BK];  // 16 KB
    __shared__ alignas(16) __hip_bfloat16 Bs[BN * BK];  // 32 KB

    const int tid  = threadIdx.x;
    const int wave = tid >> 6;         // 0..7
    const int lane = tid & 63;
    const int sub  = lane >> 3;        // staging row within 8-row chunk
    const int quad = lane >> 4;        // 0..3
    const int r16  = lane & 15;        // 0..15
    const int wm   = wave & 1;         // wave row in 2x4
    const int wn   = wave >> 1;        // wave col in 2x4 (0..3)

    // XCD-aware tile assignment: 1024 blocks = 256 M-tiles x 4 N-tiles
    const int l     = blockIdx.x;
    const int xcd   = l & (N_XCD - 1);
    const int local = l >> 3;                  // 0..127
    const int tn    = local & (TILES_N - 1);   // 0..3
    const int tm    = (xcd << 5) | (local >> 2);
    const int m0 = tm * BM;
    const int n0 = tn * BN;

    // swizzled global column for this lane's staging load
    const int scol = (((lane & 7) ^ sub) << 3);

    // staging pointers: A chunks {2w, 2w+1} (16 chunks of 8 rows),
    //                   B chunks {4w..4w+3} (32 chunks of 8 rows)
    const __hip_bfloat16* ga[2];
    const float* gaf[2];
    const __hip_bfloat16* gb[4];
    #pragma unroll
    for (int i = 0; i < 2; ++i) {
        const size_t roff = (size_t)(m0 + (wave * 2 + i) * 8 + sub) * K + scol;
        if constexpr (L1) gaf[i] = Af + roff;
        else              ga[i]  = A + roff;
    }
    #pragma unroll
    for (int i = 0; i < 4; ++i)
        gb[i] = Bt + (size_t)(n0 + (wave * 4 + i) * 8 + sub) * K + scol;

    f32x4 acc[4][4];
    #pragma unroll
    for (int i = 0; i < 4; ++i)
        #pragma unroll
        for (int j = 0; j < 4; ++j)
            acc[i][j] = (f32x4){0.f, 0.f, 0.f, 0.f};

    for (int k0 = 0; k0 < K; k0 += BK) {
        if constexpr (L1) {
            // fp32 A loads first (regs), then B DMA, then convert+ds_write:
            // the convert's vmcnt wait counts only the 4 B-gloads (counted).
            float4 v[2][2];
            #pragma unroll
            for (int i = 0; i < 2; ++i) {
                v[i][0] = *reinterpret_cast<const float4*>(gaf[i]);
                v[i][1] = *reinterpret_cast<const float4*>(gaf[i] + 4);
                gaf[i] += BK;
            }
            #pragma unroll
            for (int i = 0; i < 4; ++i) {
                async_load16(gb[i], &Bs[(wave * 4 + i) * 512]);
                gb[i] += BK;
            }
            #pragma unroll
            for (int i = 0; i < 2; ++i) {
                uint4 w;
                w.x = pack2bf(v[i][0].x, v[i][0].y);
                w.y = pack2bf(v[i][0].z, v[i][0].w);
                w.z = pack2bf(v[i][1].x, v[i][1].y);
                w.w = pack2bf(v[i][1].z, v[i][1].w);
                *reinterpret_cast<uint4*>(&As[(wave * 2 + i) * 512 + lane * 8]) = w;
            }
        } else {
            #pragma unroll
            for (int i = 0; i < 2; ++i) {
                async_load16(ga[i], &As[(wave * 2 + i) * 512]);
                ga[i] += BK;
            }
            #pragma unroll
            for (int i = 0; i < 4; ++i) {
                async_load16(gb[i], &Bs[(wave * 4 + i) * 512]);
                gb[i] += BK;
            }
        }
        __syncthreads();

        #pragma unroll
        for (int kk = 0; kk < BK; kk += 32) {
            bf16x8 af[4], bf[4];
            #pragma unroll
            for (int i = 0; i < 4; ++i) {
                int m_l = wm * 64 + i * 16 + r16;
                int sa  = ((kk >> 3) + quad) ^ (m_l & 7);
                af[i] = *reinterpret_cast<const bf16x8*>(&As[m_l * BK + sa * 8]);
                int n_l = wn * 64 + i * 16 + r16;
                int sb  = ((kk >> 3) + quad) ^ (n_l & 7);
                bf[i] = *reinterpret_cast<const bf16x8*>(&Bs[n_l * BK + sb * 8]);
            }
            // C^T accumulation: mfma(B-frag, A-frag) -> m = lane&15, regs = n
            #pragma unroll
            for (int i = 0; i < 4; ++i)
                #pragma unroll
                for (int j = 0; j < 4; ++j)
                    acc[i][j] = __builtin_amdgcn_mfma_f32_16x16x32_bf16(
                        bf[j], af[i], acc[i][j], 0, 0, 0);
        }
        __syncthreads();
    }

    if (value == nullptr) {
        // epilogue: bias + SiLU + packed 8-B stores.
        // C^T layout: row = m0+wm*64+i*16+(lane&15), n = j*16+quad*4+rr.
        #pragma unroll
        for (int j = 0; j < 4; ++j) {
            const int c0 = n0 + wn * 64 + j * 16 + quad * 4;
            const float4 b4 = *reinterpret_cast<const float4*>(&bias[c0]);
            const float* bp = reinterpret_cast<const float*>(&b4);
            #pragma unroll
            for (int i = 0; i < 4; ++i) {
                const int row = m0 + wm * 64 + i * 16 + r16;
                ushort4 o;
                unsigned short* op = reinterpret_cast<unsigned short*>(&o);
                #pragma unroll
                for (int rr = 0; rr < 4; ++rr) {
                    const float v = acc[i][j][rr] + bp[rr];
                    const float s = v / (1.f + __expf(-v));
                    op[rr] = f2bf_raw(s);
                }
                *reinterpret_cast<ushort4*>(&C[(size_t)row * H_DIM + c0]) = o;
            }
        }
    } else {
        // layer-4 epilogue: value[m] += sum_n silu(acc + bias) * Wo[n].
        float part[4];
        #pragma unroll
        for (int i = 0; i < 4; ++i) part[i] = 0.f;
        #pragma unroll
        for (int j = 0; j < 4; ++j) {
            const int c0 = n0 + wn * 64 + j * 16 + quad * 4;
            const float4 b4 = *reinterpret_cast<const float4*>(&bias[c0]);
            const float4 w4 = *reinterpret_cast<const float4*>(&Wo[c0]);
            const float* bp = reinterpret_cast<const float*>(&b4);
            const float* wp = reinterpret_cast<const float*>(&w4);
            #pragma unroll
            for (int i = 0; i < 4; ++i) {
                #pragma unroll
                for (int rr = 0; rr < 4; ++rr) {
                    const float v = acc[i][j][rr] + bp[rr];
                    const float s = v / (1.f + __expf(-v));
                    part[i] += s * wp[rr];
                }
            }
        }
        // last K-iteration ended with __syncthreads(): LDS reusable.
        float* lds_v = reinterpret_cast<float*>(As);
        #pragma unroll
        for (int i = 0; i < 4; ++i) {
            float p = part[i];
            p += __shfl_xor(p, 16, 64);
            p += __shfl_xor(p, 32, 64);
            if (quad == 0)
                lds_v[(wm * 64 + i * 16 + r16) * 4 + wn] = p;
        }
        __syncthreads();
        if (tid < BM) {
            const float* row = &lds_v[tid * 4];
            atomicAdd(&value[m0 + tid], row[0] + row[1] + row[2] + row[3]);
        }
    }
}

// ---------------------------------------------------------------------------
// GAE backward scan. value: (T,B) fp32 (pre-bias; bo added here).
// out: ret (63x512) then baseline.
// ---------------------------------------------------------------------------
__global__ __launch_bounds__(64) void gae_kernel(
    const float* __restrict__ value,
    const float* __restrict__ reward,
    const float* __restrict__ cont,
    const float* __restrict__ bo_p,
    float* __restrict__ out) {
    int b = blockIdx.x * blockDim.x + threadIdx.x;
    if (b >= B_DIM) return;
    const float bo = bo_p[0];
    float adv = 0.f;
    float v_next = value[(T_DIM - 1) * B_DIM + b] + bo;
    for (int t = T_DIM - 2; t >= 0; --t) {
        float v_t  = value[t * B_DIM + b] + bo;
        float disc = cont[(t + 1) * B_DIM + b] * DISCOUNT;
        float delta = reward[t * B_DIM + b] + disc * v_next - v_t;
        adv = delta + disc * LAM * adv;
        out[t * B_DIM + b] = adv + v_t;                           // ret
        out[(T_DIM - 1) * B_DIM + t * B_DIM + b] = v_t;           // baseline
        v_next = v_t;
    }
}

// ---------------------------------------------------------------------------
extern "C" void kernel_launch(void* const* d_in, const int* in_sizes, int n_in,
                              void* d_out, int out_size, void* d_ws, size_t ws_size,
                              hipStream_t stream) {
    const float* feat   = (const float*)d_in[0];
    const float* reward = (const float*)d_in[1];
    const float* cont   = (const float*)d_in[2];
    const float* W[4]   = {(const float*)d_in[3], (const float*)d_in[5],
                           (const float*)d_in[7], (const float*)d_in[9]};
    const float* bias[4] = {(const float*)d_in[4], (const float*)d_in[6],
                            (const float*)d_in[8], (const float*)d_in[10]};
    const float* Wo = (const float*)d_in[11];
    const float* bo = (const float*)d_in[12];
    float* out = (float*)d_out;

    // workspace layout (Xb is gone: layer 1 reads feat fp32 directly)
    char* ws = (char*)d_ws;
    __hip_bfloat16* Ha = (__hip_bfloat16*)ws; ws += (size_t)M_DIM * H_DIM * 2;   // 64 MB
    __hip_bfloat16* Hb = (__hip_bfloat16*)ws; ws += (size_t)M_DIM * H_DIM * 2;   // 64 MB
    __hip_bfloat16* Wt0 = (__hip_bfloat16*)ws; ws += (size_t)H_DIM * D_DIM * 2;  // 3 MB
    __hip_bfloat16* Wt1 = (__hip_bfloat16*)ws; ws += (size_t)H_DIM * H_DIM * 2;
    __hip_bfloat16* Wt2 = (__hip_bfloat16*)ws; ws += (size_t)H_DIM * H_DIM * 2;
    __hip_bfloat16* Wt3 = (__hip_bfloat16*)ws; ws += (size_t)H_DIM * H_DIM * 2;
    float* value = (float*)ws; ws += (size_t)M_DIM * 4;

    // 1. weight transposes (+ value zero-init), one launch
    transpose_cvt_all_kernel<<<dim3(D_DIM / 32, H_DIM / 32, 4), dim3(32, 8), 0, stream>>>(
        W[0], W[1], W[2], W[3], Wt0, Wt1, Wt2, Wt3, value);

    // 2. MLP: 4 GEMM + SiLU layers; layer 1 converts feat in-staging,
    //    layer 4 fuses the value-head GEMV
    const int nblocks = TILES_M * TILES_N;  // 1024
    gemm_silu_kernel<true><<<nblocks, 512, 0, stream>>>(
        nullptr, feat, Wt0, bias[0], Ha, D_DIM, nullptr, nullptr);
    gemm_silu_kernel<false><<<nblocks, 512, 0, stream>>>(
        Ha, nullptr, Wt1, bias[1], Hb, H_DIM, nullptr, nullptr);
    gemm_silu_kernel<false><<<nblocks, 512, 0, stream>>>(
        Hb, nullptr, Wt2, bias[2], Ha, H_DIM, nullptr, nullptr);
    gemm_silu_kernel<false><<<nblocks, 512, 0, stream>>>(
        Ha, nullptr, Wt3, bias[3], Hb, H_DIM, Wo, value);

    // 3. GAE scan (adds bo to value here)
    gae_kernel<<<8, 64, 0, stream>>>(value, reward, cont, bo, out);
}